// Round 10
// baseline (663.389 us; speedup 1.0000x reference)
//
#include <hip/hip_runtime.h>

// Quantize_78365973283370: VQ with argmax (faithful source bug: farthest cluster).
// d_in[0] = inputs [8,32,32,128] f32 (N=8192 x D=128)
// d_in[1] = cluster_mean [128,10000] f32 (column e = cluster vector)
// out (f32 concat): quantize[8192*128] | cluster_index[8192] (as float) | diff[8192]
//
// R10: two fixes over R9 (evidence: WRITE_SIZE=49MB spills + VGPR_Count=64):
//  (a) __launch_bounds__(512,2): hipcc treats arg2 as min BLOCKS/CU (CUDA semantics);
//      (512,4) forced 32 waves/CU -> 64-VGPR cap -> ~36 spilled regs. (512,2) -> 128 cap.
//  (b) cmT[10000][128] pre-transpose so the gather in merge/refine is coalesced
//      (was a 40KB-strided column walk, ~128 cache lines/sample).

#define NSAMP 8192
#define NEMB  10000
#define DIM   128
#define NS    16            // samples per block
#define TPB   512
#define HALF  (NEMB / 2)    // 5000 columns per e-half
#define CHUNK1 (TPB * 2)    // 1024 columns per chunk (2 cols/thread)
#define MARGIN 0.02f

// ---------------- prep: cluster norms in f64 (+f32 copy) ----------------
__global__ __launch_bounds__(256) void prep_c2(const float* __restrict__ cm,
                                               double* __restrict__ c2d,
                                               float* __restrict__ c2f) {
    int e = blockIdx.x * 256 + threadIdx.x;
    if (e >= NEMB) return;
    double a = 0.0;
#pragma unroll 8
    for (int d = 0; d < DIM; ++d) {
        double v = (double)cm[(size_t)d * NEMB + e];
        a = fma(v, v, a);
    }
    c2d[e] = a;
    c2f[e] = (float)a;
}

// ---------------- prep: transpose samples to sT[d][n] (LDS-tiled) ----------------
__global__ __launch_bounds__(256) void prep_sT(const float* __restrict__ smp,
                                               float* __restrict__ sT) {
    __shared__ float t[64][65];
    const int tid = threadIdx.x;
    const int bn = blockIdx.x & 127;        // n-tile (8192/64 = 128)
    const int bd = blockIdx.x >> 7;         // d-tile (128/64 = 2)
    const int n0 = bn * 64, d0 = bd * 64;
#pragma unroll
    for (int i = 0; i < 4; ++i) {
        int nloc = (tid >> 4) + i * 16;
        int dl4  = (tid & 15) * 4;
        float4 v = *(const float4*)&smp[(size_t)(n0 + nloc) * DIM + d0 + dl4];
        t[dl4 + 0][nloc] = v.x; t[dl4 + 1][nloc] = v.y;
        t[dl4 + 2][nloc] = v.z; t[dl4 + 3][nloc] = v.w;
    }
    __syncthreads();
#pragma unroll
    for (int i = 0; i < 4; ++i) {
        int dloc = (tid >> 4) + i * 16;
        int nl4  = (tid & 15) * 4;
        float4 w = make_float4(t[dloc][nl4], t[dloc][nl4 + 1], t[dloc][nl4 + 2], t[dloc][nl4 + 3]);
        *(float4*)&sT[(size_t)(d0 + dloc) * NSAMP + n0 + nl4] = w;
    }
}

// ---------------- prep: transpose cm to cmT[e][d] (LDS-tiled, 32x32) ----------------
#define ETILES 313   // ceil(10000/32)
__global__ __launch_bounds__(256) void prep_cmT(const float* __restrict__ cm,
                                                float* __restrict__ cmT) {
    __shared__ float t[32][33];
    const int tid = threadIdx.x;
    const int te = blockIdx.x % ETILES;
    const int td = blockIdx.x / ETILES;     // 0..3
    const int e0 = te * 32, d0 = td * 32;
    const int r = tid >> 5, c = tid & 31;   // r:0..7, c:0..31
#pragma unroll
    for (int i = 0; i < 4; ++i) {
        int d = d0 + r + i * 8;
        int e = e0 + c;
        if (e < NEMB) t[r + i * 8][c] = cm[(size_t)d * NEMB + e];
    }
    __syncthreads();
#pragma unroll
    for (int i = 0; i < 4; ++i) {
        int e = e0 + r + i * 8;
        int d = d0 + c;
        if (e < NEMB) cmT[(size_t)e * DIM + d] = t[c][r + i * 8];
    }
}

// ---------------- K1: f32 partial scan (per sample-group x e-half) ----------------
__global__ __launch_bounds__(TPB, 2) void vq_partial(
    const float* __restrict__ cm, const float* __restrict__ sT,
    const float* __restrict__ c2f,
    float* __restrict__ pv1, float* __restrict__ pv2, int* __restrict__ pi1)
{
    const int tid = threadIdx.x;
    const int sg   = blockIdx.x >> 1;       // sample group (512)
    const int half = blockIdx.x & 1;        // e-half
    const int s0 = sg * NS;
    const int ebeg = half * HALF, eend = ebeg + HALF;
    const int lane = tid & 63, wav = tid >> 6;

    float v1[NS], v2[NS];
    int   i1[NS];
#pragma unroll
    for (int s = 0; s < NS; ++s) { v1[s] = -3.0e38f; v2[s] = -3.0e38f; i1[s] = 0; }

#pragma unroll 1
    for (int e0 = ebeg; e0 < eend; e0 += CHUNK1) {      // 5 chunks (last partial)
        const int b0 = e0 + tid * 2;
        const int cb0 = (b0 > eend - 2) ? (eend - 2) : b0;   // clamp tail (even, 8B-aligned)
        const float* p0 = cm + cb0;

        float acc0[NS], acc1[NS];
#pragma unroll
        for (int s = 0; s < NS; ++s) { acc0[s] = 0.0f; acc1[s] = 0.0f; }

#pragma unroll 4
        for (int d = 0; d < DIM; ++d) {
            float2 cv = *(const float2*)(p0 + (size_t)d * NEMB);
            const float* sd = sT + (size_t)d * NSAMP + s0;   // wave-uniform -> s_load
#pragma unroll
            for (int s = 0; s < NS; ++s) {
                float sv = sd[s];
                acc0[s] = fmaf(cv.x, sv, acc0[s]);
                acc1[s] = fmaf(cv.y, sv, acc1[s]);
            }
        }

        float2 c0 = *(const float2*)(c2f + cb0);
        const int e_c0 = b0, e_c1 = b0 + 1;                  // ascending
        if (e_c0 < eend) {
#pragma unroll
            for (int s = 0; s < NS; ++s) {
                float sc = fmaf(-2.0f, acc0[s], c0.x);
                if (sc > v1[s]) { v2[s] = v1[s]; v1[s] = sc; i1[s] = e_c0; }
                else if (sc > v2[s]) { v2[s] = sc; }
            }
        }
        if (e_c1 < eend) {
#pragma unroll
            for (int s = 0; s < NS; ++s) {
                float sc = fmaf(-2.0f, acc1[s], c0.y);
                if (sc > v1[s]) { v2[s] = v1[s]; v1[s] = sc; i1[s] = e_c1; }
                else if (sc > v2[s]) { v2[s] = sc; }
            }
        }
    }

    // wave butterfly merge: max val (tie -> smaller idx), track second-max
#pragma unroll
    for (int s = 0; s < NS; ++s) {
#pragma unroll
        for (int m = 1; m < 64; m <<= 1) {
            float ov1 = __shfl_xor(v1[s], m, 64);
            int   oi1 = __shfl_xor(i1[s], m, 64);
            float ov2 = __shfl_xor(v2[s], m, 64);
            float nv2 = fmaxf(fminf(v1[s], ov1), fmaxf(v2[s], ov2));
            if (ov1 > v1[s] || (ov1 == v1[s] && oi1 < i1[s])) { v1[s] = ov1; i1[s] = oi1; }
            v2[s] = nv2;
        }
    }

    __shared__ float swv1[TPB / 64][NS], swv2[TPB / 64][NS];
    __shared__ int   swi[TPB / 64][NS];
    if (lane == 0) {
#pragma unroll
        for (int s = 0; s < NS; ++s) { swv1[wav][s] = v1[s]; swi[wav][s] = i1[s]; swv2[wav][s] = v2[s]; }
    }
    __syncthreads();
    if (tid < NS) {
        const int s = tid;
        float bv1 = swv1[0][s]; int bi = swi[0][s]; float bv2 = swv2[0][s];
#pragma unroll
        for (int w = 1; w < TPB / 64; ++w) {
            float av1 = swv1[w][s]; int ai = swi[w][s]; float av2 = swv2[w][s];
            float nv2 = fmaxf(fminf(bv1, av1), fmaxf(bv2, av2));
            if (av1 > bv1 || (av1 == bv1 && ai < bi)) { bv1 = av1; bi = ai; }
            bv2 = nv2;
        }
        pv1[blockIdx.x * NS + s] = bv1;
        pv2[blockIdx.x * NS + s] = bv2;
        pi1[blockIdx.x * NS + s] = bi;
    }
}

// ---------------- K2: merge halves + gather + diff (coalesced via cmT) ----------------
__global__ __launch_bounds__(128) void vq_merge(
    const float* __restrict__ cmT, const float* __restrict__ smp,
    const float* __restrict__ pv1, const float* __restrict__ pv2, const int* __restrict__ pi1,
    float* __restrict__ out_q, float* __restrict__ out_idx, float* __restrict__ out_diff,
    int* __restrict__ flag)
{
    const int s = blockIdx.x;
    const int tid = threadIdx.x;          // = d
    const int sg = s >> 4, j = s & 15;
    const int pa = (sg * 2) * NS + j, pb = (sg * 2 + 1) * NS + j;

    // all threads compute the (tiny) merge redundantly — broadcast loads
    float v1a = pv1[pa], v2a = pv2[pa]; int i1a = pi1[pa];
    float v1b = pv1[pb], v2b = pv2[pb]; int i1b = pi1[pb];
    float bv1; int bi;
    if (v1b > v1a) { bv1 = v1b; bi = i1b; } else { bv1 = v1a; bi = i1a; }  // tie -> a (smaller e)
    float bv2 = fmaxf(fminf(v1a, v1b), fmaxf(v2a, v2b));

    if (tid == 0) {
        out_idx[s] = (float)bi;
        flag[s] = (bv1 - bv2 < MARGIN) ? 1 : 0;
    }

    // gather + diff (d = tid), coalesced reads from cmT row bi
    float q = cmT[(size_t)bi * DIM + tid];
    float x = smp[(size_t)s * DIM + tid];
    out_q[(size_t)s * DIM + tid] = q;
    float t = x - q;
    float t2 = t * t;
#pragma unroll
    for (int m = 1; m < 64; m <<= 1) t2 += __shfl_xor(t2, m, 64);
    __shared__ float ws2[2];
    if ((tid & 63) == 0) ws2[tid >> 6] = t2;
    __syncthreads();
    if (tid == 0) out_diff[s] = (ws2[0] + ws2[1]) * (1.0f / DIM);
}

// ---------------- K3: exact f64 refine, one sample per block, early exit ----------------
__global__ __launch_bounds__(256) void vq_refine(
    const float* __restrict__ cm, const float* __restrict__ cmT,
    const float* __restrict__ smp,
    const double* __restrict__ c2d, const int* __restrict__ flag,
    float* __restrict__ out_q, float* __restrict__ out_idx, float* __restrict__ out_diff)
{
    const int s = blockIdx.x;
    if (!flag[s]) return;
    const int tid = threadIdx.x;
    const int lane = tid & 63, wav = tid >> 6;

    __shared__ double svd[DIM];
    __shared__ double rwv[4];
    __shared__ int    rwe[4];
    __shared__ float  dsum[4];
    __shared__ int    fin;

    if (tid < DIM) svd[tid] = (double)smp[(size_t)s * DIM + tid];
    __syncthreads();

    double bv = -1.0e300; int be = 0;
#pragma unroll 1
    for (int e0 = tid * 4; e0 < NEMB; e0 += 256 * 4) {     // ascending e per thread
        double dot[4] = {0.0, 0.0, 0.0, 0.0};
#pragma unroll 8
        for (int d = 0; d < DIM; ++d) {
            float4 cv = *(const float4*)(cm + (size_t)d * NEMB + e0);
            double sd = svd[d];
            dot[0] = fma((double)cv.x, sd, dot[0]);
            dot[1] = fma((double)cv.y, sd, dot[1]);
            dot[2] = fma((double)cv.z, sd, dot[2]);
            dot[3] = fma((double)cv.w, sd, dot[3]);
        }
#pragma unroll
        for (int k = 0; k < 4; ++k) {
            int e = e0 + k;
            double sc = fma(-2.0, dot[k], c2d[e]);
            if (sc > bv) { bv = sc; be = e; }
        }
    }
#pragma unroll
    for (int m = 1; m < 64; m <<= 1) {
        double ov = __shfl_xor(bv, m, 64);
        int    oe = __shfl_xor(be, m, 64);
        if (ov > bv || (ov == bv && oe < be)) { bv = ov; be = oe; }
    }
    if (lane == 0) { rwv[wav] = bv; rwe[wav] = be; }
    __syncthreads();
    if (tid == 0) {
        double v = rwv[0]; int e = rwe[0];
#pragma unroll
        for (int w = 1; w < 4; ++w)
            if (rwv[w] > v || (rwv[w] == v && rwe[w] < e)) { v = rwv[w]; e = rwe[w]; }
        fin = e;
        out_idx[s] = (float)e;
    }
    __syncthreads();
    const int e = fin;
    float t2 = 0.0f;
    if (tid < DIM) {
        float q = cmT[(size_t)e * DIM + tid];
        float x = smp[(size_t)s * DIM + tid];
        out_q[(size_t)s * DIM + tid] = q;
        float t = x - q;
        t2 = t * t;
    }
#pragma unroll
    for (int m = 1; m < 64; m <<= 1) t2 += __shfl_xor(t2, m, 64);
    if (lane == 0) dsum[wav] = t2;
    __syncthreads();
    if (tid == 0) out_diff[s] = (dsum[0] + dsum[1] + dsum[2] + dsum[3]) * (1.0f / DIM);
}

extern "C" void kernel_launch(void* const* d_in, const int* in_sizes, int n_in,
                              void* d_out, int out_size, void* d_ws, size_t ws_size,
                              hipStream_t stream) {
    const float* smp = (const float*)d_in[0];   // [8192,128]
    const float* cm  = (const float*)d_in[1];   // [128,10000]

    float* out      = (float*)d_out;
    float* out_q    = out;
    float* out_idx  = out + (size_t)NSAMP * DIM;
    float* out_diff = out_idx + NSAMP;

    char* ws = (char*)d_ws;
    double* c2d = (double*)ws;                               // 80000 B
    float*  c2f = (float*)(ws + 80000);                      // 40000 B
    float*  sT  = (float*)(ws + 120064);                     // 4 MB (16B aligned)
    float*  cmT = (float*)(ws + 120064 + 4194304);           // 5.12 MB
    char*   p   = ws + 120064 + 4194304 + 5120000;
    float*  pv1 = (float*)p;                                 // 65536
    float*  pv2 = (float*)(p + 65536);
    int*    pi1 = (int*)  (p + 131072);
    int*    flag= (int*)  (p + 196608);                      // 32768

    prep_c2<<<(NEMB + 255) / 256, 256, 0, stream>>>(cm, c2d, c2f);
    prep_sT<<<256, 256, 0, stream>>>(smp, sT);
    prep_cmT<<<ETILES * 4, 256, 0, stream>>>(cm, cmT);
    vq_partial<<<(NSAMP / NS) * 2, TPB, 0, stream>>>(cm, sT, c2f, pv1, pv2, pi1);
    vq_merge<<<NSAMP, 128, 0, stream>>>(cmT, smp, pv1, pv2, pi1, out_q, out_idx, out_diff, flag);
    vq_refine<<<NSAMP, 256, 0, stream>>>(cm, cmT, smp, c2d, flag, out_q, out_idx, out_diff);
}

// Round 11
// 611.513 us; speedup vs baseline: 1.0848x; 1.0848x over previous
//
#include <hip/hip_runtime.h>

// Quantize_78365973283370: VQ with argmax (faithful source bug: farthest cluster).
// d_in[0] = inputs [8,32,32,128] f32 (N=8192 x D=128)
// d_in[1] = cluster_mean [128,10000] f32 (column e = cluster vector)
// out (f32 concat): quantize[8192*128] | cluster_index[8192] (as float) | diff[8192]
//
// R11: kill the per-(thread,sample) top-2 register state (48 VGPR) that starved the
// allocator in R9/R10 (VALU busy ~330us vs 133us FMA floor = acc/state shuffling).
// Per chunk each thread has only a 2-candidate pair; an exact top-2 wave butterfly
// (6 shfl steps) + lane0 RMW of per-wave LDS state replaces all cross-chunk registers.
// Samples via LDS broadcast tile (uniform-address reads are conflict-free, m136).
// Flagged samples (gap < MARGIN) re-scanned exactly in f64 (proven vs R1).

#define NSAMP 8192
#define NEMB  10000
#define DIM   128
#define NS    16            // samples per block
#define TPB   512
#define NWAVE (TPB / 64)
#define HALF  (NEMB / 2)    // 5000 columns per e-half
#define CHUNK (TPB * 2)     // 1024 columns per chunk (2 cols/thread) -> 5 chunks/half
#define MARGIN 0.02f

// ---------------- prep: cluster norms in f64 (+f32 copy) ----------------
__global__ __launch_bounds__(256) void prep_c2(const float* __restrict__ cm,
                                               double* __restrict__ c2d,
                                               float* __restrict__ c2f) {
    int e = blockIdx.x * 256 + threadIdx.x;
    if (e >= NEMB) return;
    double a = 0.0;
#pragma unroll 8
    for (int d = 0; d < DIM; ++d) {
        double v = (double)cm[(size_t)d * NEMB + e];
        a = fma(v, v, a);
    }
    c2d[e] = a;
    c2f[e] = (float)a;
}

// ---------------- K1: f32 scan, butterfly top-2 per chunk ----------------
__global__ __launch_bounds__(TPB, 3) void vq_scan(
    const float* __restrict__ cm, const float* __restrict__ smp,
    const float* __restrict__ c2f,
    float* __restrict__ pv1, float* __restrict__ pv2, int* __restrict__ pi1)
{
    const int tid = threadIdx.x;
    const int sg   = blockIdx.x >> 1;       // sample group (512)
    const int half = blockIdx.x & 1;        // e-half
    const int s0 = sg * NS;
    const int ebeg = half * HALF, eend = ebeg + HALF;
    const int lane = tid & 63, wav = tid >> 6;

    __shared__ float ssv[DIM][NS];          // sample broadcast tile, 8 KB
    __shared__ float wv1[NWAVE][NS], wv2[NWAVE][NS];
    __shared__ int   wi1[NWAVE][NS];

#pragma unroll
    for (int i = 0; i < (DIM * NS) / TPB; ++i) {   // 4 iters, coalesced
        int gid = i * TPB + tid;
        int n = gid >> 7;
        int d = gid & (DIM - 1);
        ssv[d][n] = smp[(size_t)(s0 + n) * DIM + d];
    }
    if (tid < NWAVE * NS) {
        int w = tid >> 4, s = tid & 15;
        wv1[w][s] = -3.0e38f; wv2[w][s] = -3.0e38f; wi1[w][s] = 0;
    }
    __syncthreads();

#pragma unroll 1
    for (int e0 = ebeg; e0 < eend; e0 += CHUNK) {      // 5 chunks (last partial)
        const int b0 = e0 + tid * 2;
        const bool valid = (b0 <= eend - 2);
        const int cb0 = valid ? b0 : (eend - 2);        // clamped addr, scores voided
        const float* p0 = cm + cb0;

        float acc0[NS], acc1[NS];
#pragma unroll
        for (int s = 0; s < NS; ++s) { acc0[s] = 0.0f; acc1[s] = 0.0f; }

#pragma unroll 4
        for (int d = 0; d < DIM; ++d) {
            float2 cv = *(const float2*)(p0 + (size_t)d * NEMB);
            const float4* sp = (const float4*)&ssv[d][0];   // uniform addr -> broadcast
            float4 q0 = sp[0], q1 = sp[1], q2 = sp[2], q3 = sp[3];
            float sv_[NS] = {q0.x, q0.y, q0.z, q0.w, q1.x, q1.y, q1.z, q1.w,
                             q2.x, q2.y, q2.z, q2.w, q3.x, q3.y, q3.z, q3.w};
#pragma unroll
            for (int s = 0; s < NS; ++s) {
                acc0[s] = fmaf(cv.x, sv_[s], acc0[s]);
                acc1[s] = fmaf(cv.y, sv_[s], acc1[s]);
            }
        }

        float2 c0 = *(const float2*)(c2f + cb0);
#pragma unroll 1
        for (int s = 0; s < NS; ++s) {
            float sc0 = valid ? fmaf(-2.0f, acc0[s], c0.x) : -3.0e38f;
            float sc1 = valid ? fmaf(-2.0f, acc1[s], c0.y) : -3.0e38f;
            // local top-2 of the pair (tie -> smaller index = b0)
            float v1, v2; int i1;
            if (sc1 > sc0) { v1 = sc1; i1 = b0 + 1; v2 = sc0; }
            else           { v1 = sc0; i1 = b0;     v2 = sc1; }
            // exact top-2 wave butterfly
#pragma unroll
            for (int m = 1; m < 64; m <<= 1) {
                float ov1 = __shfl_xor(v1, m, 64);
                int   oi1 = __shfl_xor(i1, m, 64);
                float ov2 = __shfl_xor(v2, m, 64);
                float nv2 = fmaxf(fminf(v1, ov1), fmaxf(v2, ov2));
                if (ov1 > v1 || (ov1 == v1 && oi1 < i1)) { v1 = ov1; i1 = oi1; }
                v2 = nv2;
            }
            if (lane == 0) {   // RMW per-wave LDS state (wave-private, no barrier)
                float bv1 = wv1[wav][s]; int bi = wi1[wav][s]; float bv2 = wv2[wav][s];
                float nv2 = fmaxf(fminf(bv1, v1), fmaxf(bv2, v2));
                if (v1 > bv1 || (v1 == bv1 && i1 < bi)) { bv1 = v1; bi = i1; }
                wv1[wav][s] = bv1; wi1[wav][s] = bi; wv2[wav][s] = nv2;
            }
        }
    }
    __syncthreads();

    if (tid < NS) {
        const int s = tid;
        float bv1 = wv1[0][s]; int bi = wi1[0][s]; float bv2 = wv2[0][s];
#pragma unroll
        for (int w = 1; w < NWAVE; ++w) {
            float av1 = wv1[w][s]; int ai = wi1[w][s]; float av2 = wv2[w][s];
            float nv2 = fmaxf(fminf(bv1, av1), fmaxf(bv2, av2));
            if (av1 > bv1 || (av1 == bv1 && ai < bi)) { bv1 = av1; bi = ai; }
            bv2 = nv2;
        }
        pv1[blockIdx.x * NS + s] = bv1;
        pv2[blockIdx.x * NS + s] = bv2;
        pi1[blockIdx.x * NS + s] = bi;
    }
}

// ---------------- K2: merge halves + gather + diff ----------------
__global__ __launch_bounds__(128) void vq_merge(
    const float* __restrict__ cm, const float* __restrict__ smp,
    const float* __restrict__ pv1, const float* __restrict__ pv2, const int* __restrict__ pi1,
    float* __restrict__ out_q, float* __restrict__ out_idx, float* __restrict__ out_diff,
    int* __restrict__ flag)
{
    const int s = blockIdx.x;
    const int tid = threadIdx.x;          // = d
    const int sg = s >> 4, j = s & 15;
    const int pa = (sg * 2) * NS + j, pb = (sg * 2 + 1) * NS + j;

    float v1a = pv1[pa], v2a = pv2[pa]; int i1a = pi1[pa];
    float v1b = pv1[pb], v2b = pv2[pb]; int i1b = pi1[pb];
    float bv1; int bi;
    if (v1b > v1a) { bv1 = v1b; bi = i1b; } else { bv1 = v1a; bi = i1a; }  // tie -> a (smaller e)
    float bv2 = fmaxf(fminf(v1a, v1b), fmaxf(v2a, v2b));

    if (tid == 0) {
        out_idx[s] = (float)bi;
        flag[s] = (bv1 - bv2 < MARGIN) ? 1 : 0;
    }

    float q = cm[(size_t)tid * NEMB + bi];
    float x = smp[(size_t)s * DIM + tid];
    out_q[(size_t)s * DIM + tid] = q;
    float t = x - q;
    float t2 = t * t;
#pragma unroll
    for (int m = 1; m < 64; m <<= 1) t2 += __shfl_xor(t2, m, 64);
    __shared__ float ws2[2];
    if ((tid & 63) == 0) ws2[tid >> 6] = t2;
    __syncthreads();
    if (tid == 0) out_diff[s] = (ws2[0] + ws2[1]) * (1.0f / DIM);
}

// ---------------- K3: exact f64 refine, one sample per block, early exit ----------------
__global__ __launch_bounds__(256) void vq_refine(
    const float* __restrict__ cm, const float* __restrict__ smp,
    const double* __restrict__ c2d, const int* __restrict__ flag,
    float* __restrict__ out_q, float* __restrict__ out_idx, float* __restrict__ out_diff)
{
    const int s = blockIdx.x;
    if (!flag[s]) return;
    const int tid = threadIdx.x;
    const int lane = tid & 63, wav = tid >> 6;

    __shared__ double svd[DIM];
    __shared__ double rwv[4];
    __shared__ int    rwe[4];
    __shared__ float  dsum[4];
    __shared__ int    fin;

    if (tid < DIM) svd[tid] = (double)smp[(size_t)s * DIM + tid];
    __syncthreads();

    double bv = -1.0e300; int be = 0;
#pragma unroll 1
    for (int e0 = tid * 4; e0 < NEMB; e0 += 256 * 4) {
        double dot[4] = {0.0, 0.0, 0.0, 0.0};
#pragma unroll 8
        for (int d = 0; d < DIM; ++d) {
            float4 cv = *(const float4*)(cm + (size_t)d * NEMB + e0);
            double sd = svd[d];
            dot[0] = fma((double)cv.x, sd, dot[0]);
            dot[1] = fma((double)cv.y, sd, dot[1]);
            dot[2] = fma((double)cv.z, sd, dot[2]);
            dot[3] = fma((double)cv.w, sd, dot[3]);
        }
#pragma unroll
        for (int k = 0; k < 4; ++k) {
            int e = e0 + k;
            double sc = fma(-2.0, dot[k], c2d[e]);
            if (sc > bv) { bv = sc; be = e; }
        }
    }
#pragma unroll
    for (int m = 1; m < 64; m <<= 1) {
        double ov = __shfl_xor(bv, m, 64);
        int    oe = __shfl_xor(be, m, 64);
        if (ov > bv || (ov == bv && oe < be)) { bv = ov; be = oe; }
    }
    if (lane == 0) { rwv[wav] = bv; rwe[wav] = be; }
    __syncthreads();
    if (tid == 0) {
        double v = rwv[0]; int e = rwe[0];
#pragma unroll
        for (int w = 1; w < 4; ++w)
            if (rwv[w] > v || (rwv[w] == v && rwe[w] < e)) { v = rwv[w]; e = rwe[w]; }
        fin = e;
        out_idx[s] = (float)e;
    }
    __syncthreads();
    const int e = fin;
    float t2 = 0.0f;
    if (tid < DIM) {
        float q = cm[(size_t)tid * NEMB + e];
        float x = smp[(size_t)s * DIM + tid];
        out_q[(size_t)s * DIM + tid] = q;
        float t = x - q;
        t2 = t * t;
    }
#pragma unroll
    for (int m = 1; m < 64; m <<= 1) t2 += __shfl_xor(t2, m, 64);
    if (lane == 0) dsum[wav] = t2;
    __syncthreads();
    if (tid == 0) out_diff[s] = (dsum[0] + dsum[1] + dsum[2] + dsum[3]) * (1.0f / DIM);
}

extern "C" void kernel_launch(void* const* d_in, const int* in_sizes, int n_in,
                              void* d_out, int out_size, void* d_ws, size_t ws_size,
                              hipStream_t stream) {
    const float* smp = (const float*)d_in[0];   // [8192,128]
    const float* cm  = (const float*)d_in[1];   // [128,10000]

    float* out      = (float*)d_out;
    float* out_q    = out;
    float* out_idx  = out + (size_t)NSAMP * DIM;
    float* out_diff = out_idx + NSAMP;

    char* ws = (char*)d_ws;
    double* c2d  = (double*)ws;                  // 80000 B
    float*  c2f  = (float*)(ws + 80000);         // 40000 B
    char*   p    = ws + 120064;                  // 16B aligned
    float*  pv1  = (float*)p;                    // 1024*16*4 = 65536
    float*  pv2  = (float*)(p + 65536);
    int*    pi1  = (int*)  (p + 131072);
    int*    flag = (int*)  (p + 196608);         // 32768

    prep_c2<<<(NEMB + 255) / 256, 256, 0, stream>>>(cm, c2d, c2f);
    vq_scan<<<(NSAMP / NS) * 2, TPB, 0, stream>>>(cm, smp, c2f, pv1, pv2, pi1);
    vq_merge<<<NSAMP, 128, 0, stream>>>(cm, smp, pv1, pv2, pi1, out_q, out_idx, out_diff, flag);
    vq_refine<<<NSAMP, 256, 0, stream>>>(cm, smp, c2d, flag, out_q, out_idx, out_diff);
}

// Round 12
// 556.746 us; speedup vs baseline: 1.1915x; 1.0984x over previous
//
#include <hip/hip_runtime.h>

// Quantize_78365973283370: VQ with argmax (faithful source bug: farthest cluster).
// d_in[0] = inputs [8,32,32,128] f32 (N=8192 x D=128)
// d_in[1] = cluster_mean [128,10000] f32 (column e = cluster vector)
// out (f32 concat): quantize[8192*128] | cluster_index[8192] (as float) | diff[8192]
//
// R12: the R9/R11 plateau was the SCALAR v_fma_f32 wall (78.6 TF; busy-time ~300us =
// 21 GFLOP / 78.6 TF). MI355X's 157.3 TF f32 requires packed v_pk_fma_f32 -> emit it
// via inline asm. acc pair = (e0,e1) cols per sample; cv = contiguous f32x2 load;
// sample operand = (sv,sv) SGPR pair from a pre-duplicated sdup[d][2n] array read at
// wave-uniform addresses (s_load, proven R9). Butterfly top-2 + LDS wave state (R11).

typedef __attribute__((ext_vector_type(2))) float f32x2;

#define NSAMP 8192
#define NEMB  10000
#define DIM   128
#define NS    16            // samples per block
#define TPB   512
#define NWAVE (TPB / 64)
#define HALF  (NEMB / 2)    // 5000 columns per e-half
#define CHUNK (TPB * 2)     // 1024 columns per chunk (2 cols/thread) -> 5 chunks/half
#define MARGIN 0.02f

// ---------------- prep: cluster norms in f64 (+f32 copy) ----------------
__global__ __launch_bounds__(256) void prep_c2(const float* __restrict__ cm,
                                               double* __restrict__ c2d,
                                               float* __restrict__ c2f) {
    int e = blockIdx.x * 256 + threadIdx.x;
    if (e >= NEMB) return;
    double a = 0.0;
#pragma unroll 8
    for (int d = 0; d < DIM; ++d) {
        double v = (double)cm[(size_t)d * NEMB + e];
        a = fma(v, v, a);
    }
    c2d[e] = a;
    c2f[e] = (float)a;
}

// ---------------- prep: transpose+duplicate samples to sdup[d][2n]=[2n+1]=s[n][d] ----------------
__global__ __launch_bounds__(256) void prep_sdup(const float* __restrict__ smp,
                                                 float* __restrict__ sdup) {
    __shared__ float t[64][65];
    const int tid = threadIdx.x;
    const int bn = blockIdx.x & 127;        // n-tile (8192/64 = 128)
    const int bd = blockIdx.x >> 7;         // d-tile (128/64 = 2)
    const int n0 = bn * 64, d0 = bd * 64;
#pragma unroll
    for (int i = 0; i < 4; ++i) {
        int nloc = (tid >> 4) + i * 16;
        int dl4  = (tid & 15) * 4;
        float4 v = *(const float4*)&smp[(size_t)(n0 + nloc) * DIM + d0 + dl4];
        t[dl4 + 0][nloc] = v.x; t[dl4 + 1][nloc] = v.y;
        t[dl4 + 2][nloc] = v.z; t[dl4 + 3][nloc] = v.w;
    }
    __syncthreads();
#pragma unroll
    for (int i = 0; i < 8; ++i) {
        int id = i * 256 + tid;             // 0..2047
        int dloc = id >> 5;                 // 0..63
        int nl2  = id & 31;                 // pair-of-n index
        float v0 = t[dloc][nl2 * 2], v1 = t[dloc][nl2 * 2 + 1];
        *(float4*)&sdup[(size_t)(d0 + dloc) * (2 * NSAMP) + (size_t)(n0 + nl2 * 2) * 2] =
            make_float4(v0, v0, v1, v1);
    }
}

// ---------------- K1: packed-f32 scan, butterfly top-2 per chunk ----------------
__global__ __launch_bounds__(TPB, 3) void vq_scan(
    const float* __restrict__ cm, const float* __restrict__ sdup,
    const float* __restrict__ c2f,
    float* __restrict__ pv1, float* __restrict__ pv2, int* __restrict__ pi1)
{
    const int tid = threadIdx.x;
    const int sg   = blockIdx.x >> 1;       // sample group (512)
    const int half = blockIdx.x & 1;        // e-half
    const int s0 = sg * NS;
    const int ebeg = half * HALF, eend = ebeg + HALF;
    const int lane = tid & 63, wav = tid >> 6;

    __shared__ float wv1[NWAVE][NS], wv2[NWAVE][NS];
    __shared__ int   wi1[NWAVE][NS];
    if (tid < NWAVE * NS) {
        int w = tid >> 4, s = tid & 15;
        wv1[w][s] = -3.0e38f; wv2[w][s] = -3.0e38f; wi1[w][s] = 0;
    }
    __syncthreads();

#pragma unroll 1
    for (int e0 = ebeg; e0 < eend; e0 += CHUNK) {      // 5 chunks (last partial)
        const int b0 = e0 + tid * 2;
        const bool valid = (b0 <= eend - 2);
        const int cb0 = valid ? b0 : (eend - 2);        // clamped addr, scores voided
        const float* p0 = cm + cb0;

        f32x2 acc[NS];
#pragma unroll
        for (int s = 0; s < NS; ++s) acc[s] = (f32x2){0.0f, 0.0f};

#pragma unroll 4
        for (int d = 0; d < DIM; ++d) {
            f32x2 cv = *(const f32x2*)(p0 + (size_t)d * NEMB);
            // wave-uniform row of duplicated sample pairs -> s_load (SGPR pairs)
            const f32x2* srow = (const f32x2*)(sdup + (size_t)d * (2 * NSAMP) + 2 * s0);
            f32x2 svv[NS];
#pragma unroll
            for (int s = 0; s < NS; ++s) svv[s] = srow[s];
#pragma unroll
            for (int s = 0; s < NS; ++s) {
                asm("v_pk_fma_f32 %0, %1, %2, %0"
                    : "+v"(acc[s])
                    : "v"(cv), "s"(svv[s]));
            }
        }

        float2 c0 = *(const float2*)(c2f + cb0);
#pragma unroll 1
        for (int s = 0; s < NS; ++s) {
            float sc0 = valid ? fmaf(-2.0f, acc[s].x, c0.x) : -3.0e38f;
            float sc1 = valid ? fmaf(-2.0f, acc[s].y, c0.y) : -3.0e38f;
            // local top-2 of the pair (tie -> smaller index = b0)
            float v1, v2; int i1;
            if (sc1 > sc0) { v1 = sc1; i1 = b0 + 1; v2 = sc0; }
            else           { v1 = sc0; i1 = b0;     v2 = sc1; }
            // exact top-2 wave butterfly
#pragma unroll
            for (int m = 1; m < 64; m <<= 1) {
                float ov1 = __shfl_xor(v1, m, 64);
                int   oi1 = __shfl_xor(i1, m, 64);
                float ov2 = __shfl_xor(v2, m, 64);
                float nv2 = fmaxf(fminf(v1, ov1), fmaxf(v2, ov2));
                if (ov1 > v1 || (ov1 == v1 && oi1 < i1)) { v1 = ov1; i1 = oi1; }
                v2 = nv2;
            }
            if (lane == 0) {   // RMW per-wave LDS state (wave-private, no barrier)
                float bv1 = wv1[wav][s]; int bi = wi1[wav][s]; float bv2 = wv2[wav][s];
                float nv2 = fmaxf(fminf(bv1, v1), fmaxf(bv2, v2));
                if (v1 > bv1 || (v1 == bv1 && i1 < bi)) { bv1 = v1; bi = i1; }
                wv1[wav][s] = bv1; wi1[wav][s] = bi; wv2[wav][s] = nv2;
            }
        }
    }
    __syncthreads();

    if (tid < NS) {
        const int s = tid;
        float bv1 = wv1[0][s]; int bi = wi1[0][s]; float bv2 = wv2[0][s];
#pragma unroll
        for (int w = 1; w < NWAVE; ++w) {
            float av1 = wv1[w][s]; int ai = wi1[w][s]; float av2 = wv2[w][s];
            float nv2 = fmaxf(fminf(bv1, av1), fmaxf(bv2, av2));
            if (av1 > bv1 || (av1 == bv1 && ai < bi)) { bv1 = av1; bi = ai; }
            bv2 = nv2;
        }
        pv1[blockIdx.x * NS + s] = bv1;
        pv2[blockIdx.x * NS + s] = bv2;
        pi1[blockIdx.x * NS + s] = bi;
    }
}

// ---------------- K2: merge halves + gather + diff ----------------
__global__ __launch_bounds__(128) void vq_merge(
    const float* __restrict__ cm, const float* __restrict__ smp,
    const float* __restrict__ pv1, const float* __restrict__ pv2, const int* __restrict__ pi1,
    float* __restrict__ out_q, float* __restrict__ out_idx, float* __restrict__ out_diff,
    int* __restrict__ flag)
{
    const int s = blockIdx.x;
    const int tid = threadIdx.x;          // = d
    const int sg = s >> 4, j = s & 15;
    const int pa = (sg * 2) * NS + j, pb = (sg * 2 + 1) * NS + j;

    float v1a = pv1[pa], v2a = pv2[pa]; int i1a = pi1[pa];
    float v1b = pv1[pb], v2b = pv2[pb]; int i1b = pi1[pb];
    float bv1; int bi;
    if (v1b > v1a) { bv1 = v1b; bi = i1b; } else { bv1 = v1a; bi = i1a; }  // tie -> a (smaller e)
    float bv2 = fmaxf(fminf(v1a, v1b), fmaxf(v2a, v2b));

    if (tid == 0) {
        out_idx[s] = (float)bi;
        flag[s] = (bv1 - bv2 < MARGIN) ? 1 : 0;
    }

    float q = cm[(size_t)tid * NEMB + bi];
    float x = smp[(size_t)s * DIM + tid];
    out_q[(size_t)s * DIM + tid] = q;
    float t = x - q;
    float t2 = t * t;
#pragma unroll
    for (int m = 1; m < 64; m <<= 1) t2 += __shfl_xor(t2, m, 64);
    __shared__ float ws2[2];
    if ((tid & 63) == 0) ws2[tid >> 6] = t2;
    __syncthreads();
    if (tid == 0) out_diff[s] = (ws2[0] + ws2[1]) * (1.0f / DIM);
}

// ---------------- K3: exact f64 refine, one sample per block, early exit ----------------
__global__ __launch_bounds__(256) void vq_refine(
    const float* __restrict__ cm, const float* __restrict__ smp,
    const double* __restrict__ c2d, const int* __restrict__ flag,
    float* __restrict__ out_q, float* __restrict__ out_idx, float* __restrict__ out_diff)
{
    const int s = blockIdx.x;
    if (!flag[s]) return;
    const int tid = threadIdx.x;
    const int lane = tid & 63, wav = tid >> 6;

    __shared__ double svd[DIM];
    __shared__ double rwv[4];
    __shared__ int    rwe[4];
    __shared__ float  dsum[4];
    __shared__ int    fin;

    if (tid < DIM) svd[tid] = (double)smp[(size_t)s * DIM + tid];
    __syncthreads();

    double bv = -1.0e300; int be = 0;
#pragma unroll 1
    for (int e0 = tid * 4; e0 < NEMB; e0 += 256 * 4) {
        double dot[4] = {0.0, 0.0, 0.0, 0.0};
#pragma unroll 8
        for (int d = 0; d < DIM; ++d) {
            float4 cv = *(const float4*)(cm + (size_t)d * NEMB + e0);
            double sd = svd[d];
            dot[0] = fma((double)cv.x, sd, dot[0]);
            dot[1] = fma((double)cv.y, sd, dot[1]);
            dot[2] = fma((double)cv.z, sd, dot[2]);
            dot[3] = fma((double)cv.w, sd, dot[3]);
        }
#pragma unroll
        for (int k = 0; k < 4; ++k) {
            int e = e0 + k;
            double sc = fma(-2.0, dot[k], c2d[e]);
            if (sc > bv) { bv = sc; be = e; }
        }
    }
#pragma unroll
    for (int m = 1; m < 64; m <<= 1) {
        double ov = __shfl_xor(bv, m, 64);
        int    oe = __shfl_xor(be, m, 64);
        if (ov > bv || (ov == bv && oe < be)) { bv = ov; be = oe; }
    }
    if (lane == 0) { rwv[wav] = bv; rwe[wav] = be; }
    __syncthreads();
    if (tid == 0) {
        double v = rwv[0]; int e = rwe[0];
#pragma unroll
        for (int w = 1; w < 4; ++w)
            if (rwv[w] > v || (rwv[w] == v && rwe[w] < e)) { v = rwv[w]; e = rwe[w]; }
        fin = e;
        out_idx[s] = (float)e;
    }
    __syncthreads();
    const int e = fin;
    float t2 = 0.0f;
    if (tid < DIM) {
        float q = cm[(size_t)tid * NEMB + e];
        float x = smp[(size_t)s * DIM + tid];
        out_q[(size_t)s * DIM + tid] = q;
        float t = x - q;
        t2 = t * t;
    }
#pragma unroll
    for (int m = 1; m < 64; m <<= 1) t2 += __shfl_xor(t2, m, 64);
    if (lane == 0) dsum[wav] = t2;
    __syncthreads();
    if (tid == 0) out_diff[s] = (dsum[0] + dsum[1] + dsum[2] + dsum[3]) * (1.0f / DIM);
}

extern "C" void kernel_launch(void* const* d_in, const int* in_sizes, int n_in,
                              void* d_out, int out_size, void* d_ws, size_t ws_size,
                              hipStream_t stream) {
    const float* smp = (const float*)d_in[0];   // [8192,128]
    const float* cm  = (const float*)d_in[1];   // [128,10000]

    float* out      = (float*)d_out;
    float* out_q    = out;
    float* out_idx  = out + (size_t)NSAMP * DIM;
    float* out_diff = out_idx + NSAMP;

    char* ws = (char*)d_ws;
    double* c2d  = (double*)ws;                          // 80000 B
    float*  c2f  = (float*)(ws + 80000);                 // 40000 B
    float*  sdup = (float*)(ws + 120064);                // 8 MB (16B aligned)
    char*   p    = ws + 120064 + 8388608;
    float*  pv1  = (float*)p;                            // 1024*16*4 = 65536
    float*  pv2  = (float*)(p + 65536);
    int*    pi1  = (int*)  (p + 131072);
    int*    flag = (int*)  (p + 196608);                 // 32768

    prep_c2<<<(NEMB + 255) / 256, 256, 0, stream>>>(cm, c2d, c2f);
    prep_sdup<<<256, 256, 0, stream>>>(smp, sdup);
    vq_scan<<<(NSAMP / NS) * 2, TPB, 0, stream>>>(cm, sdup, c2f, pv1, pv2, pi1);
    vq_merge<<<NSAMP, 128, 0, stream>>>(cm, smp, pv1, pv2, pi1, out_q, out_idx, out_diff, flag);
    vq_refine<<<NSAMP, 256, 0, stream>>>(cm, smp, c2d, flag, out_q, out_idx, out_diff);
}

// Round 15
// 355.664 us; speedup vs baseline: 1.8652x; 1.5654x over previous
//
#include <hip/hip_runtime.h>

// Quantize_78365973283370: VQ with argmax (faithful source bug: farthest cluster).
// d_in[0] = inputs [8,32,32,128] f32 (N=8192 x D=128)
// d_in[1] = cluster_mean [128,10000] f32 (column e = cluster vector)
// out (f32 concat): quantize[8192*128] | cluster_index[8192] (as float) | diff[8192]
//
// R13: the f32 VALU is the wall (R9/R11/R12 all ~290us busy ~= 157TF scalar-fma limit;
// v_pk_fma_f32 is NOT 2x on CDNA4). Move the 21 GFLOP to the MATRIX pipe via bf16
// split-GEMM: x = hi + lo (RNE bf16 pair), dot ~= hi*hi + hi*lo + lo*hi (error <~2e-3,
// 10x under MARGIN=0.02; lo*lo dropped). mfma_f32_16x16x32_bf16, fragments pre-packed:
// A/B lane = idx&15, k = (lane>>4)*8+j ; D col=lane&15, row=(lane>>4)*4+reg (verified
// guide layout). Block = 16 samples x ALL cols (4 waves stride 625 e-tiles) -> per-lane
// top-2, 4-step butterfly, LDS wave merge, fused gather/diff. f64 refine net unchanged.

typedef __attribute__((ext_vector_type(8))) short bf16x8;
typedef __attribute__((ext_vector_type(4))) float f32x4;

#define NSAMP 8192
#define NEMB  10000
#define DIM   128
#define NTILE 625           // 10000 / 16
#define MARGIN 0.02f

__device__ inline ushort f2bf(float x) {            // RNE f32 -> bf16
    unsigned u = __float_as_uint(x);
    unsigned r = (u + 0x7FFFu + ((u >> 16) & 1u)) >> 16;
    return (ushort)r;
}
__device__ inline float bf2f(ushort h) { return __uint_as_float(((unsigned)h) << 16); }

// ---------------- prep: cluster norms in f64 (+f32 copy) ----------------
__global__ __launch_bounds__(256) void prep_c2(const float* __restrict__ cm,
                                               double* __restrict__ c2d,
                                               float* __restrict__ c2f) {
    int e = blockIdx.x * 256 + threadIdx.x;
    if (e >= NEMB) return;
    double a = 0.0;
#pragma unroll 8
    for (int d = 0; d < DIM; ++d) {
        double v = (double)cm[(size_t)d * NEMB + e];
        a = fma(v, v, a);
    }
    c2d[e] = a;
    c2f[e] = (float)a;
}

// ---------------- prep: pack A (samples) fragments, hi/lo split ----------------
// aPk[((mt*4+ks)*64+lane)*8 + j] = bf16(smp[mt*16+(lane&15)][ks*32+(lane>>4)*8+j])
__global__ __launch_bounds__(256) void prep_apk(const float* __restrict__ smp,
                                                ushort* __restrict__ aHi,
                                                ushort* __restrict__ aLo) {
    int gid = blockIdx.x * 256 + threadIdx.x;       // 0..131071
    int lane = gid & 63;
    int ks = (gid >> 6) & 3;
    int mt = gid >> 8;
    int m = mt * 16 + (lane & 15);
    int d0 = ks * 32 + (lane >> 4) * 8;
    const float* src = smp + (size_t)m * DIM + d0;
    unsigned hv[4], lv[4];
#pragma unroll
    for (int p = 0; p < 4; ++p) {
        float x0 = src[2 * p], x1 = src[2 * p + 1];
        ushort h0 = f2bf(x0), h1 = f2bf(x1);
        ushort l0 = f2bf(x0 - bf2f(h0)), l1 = f2bf(x1 - bf2f(h1));
        hv[p] = (unsigned)h0 | ((unsigned)h1 << 16);
        lv[p] = (unsigned)l0 | ((unsigned)l1 << 16);
    }
    *(uint4*)(aHi + (size_t)gid * 8) = make_uint4(hv[0], hv[1], hv[2], hv[3]);
    *(uint4*)(aLo + (size_t)gid * 8) = make_uint4(lv[0], lv[1], lv[2], lv[3]);
}

// ---------------- prep: pack B (cm) fragments, hi/lo split ----------------
// bPk[((et*4+ks)*64+lane)*8 + j] = bf16(cm[ks*32+(lane>>4)*8+j][et*16+(lane&15)])
__global__ __launch_bounds__(256) void prep_bpk(const float* __restrict__ cm,
                                                ushort* __restrict__ bHi,
                                                ushort* __restrict__ bLo) {
    int gid = blockIdx.x * 256 + threadIdx.x;       // 0..159999 (625*256)
    int lane = gid & 63;
    int ks = (gid >> 6) & 3;
    int et = gid >> 8;
    int e = et * 16 + (lane & 15);
    int d0 = ks * 32 + (lane >> 4) * 8;
    unsigned hv[4], lv[4];
#pragma unroll
    for (int p = 0; p < 4; ++p) {
        float x0 = cm[(size_t)(d0 + 2 * p) * NEMB + e];
        float x1 = cm[(size_t)(d0 + 2 * p + 1) * NEMB + e];
        ushort h0 = f2bf(x0), h1 = f2bf(x1);
        ushort l0 = f2bf(x0 - bf2f(h0)), l1 = f2bf(x1 - bf2f(h1));
        hv[p] = (unsigned)h0 | ((unsigned)h1 << 16);
        lv[p] = (unsigned)l0 | ((unsigned)l1 << 16);
    }
    *(uint4*)(bHi + (size_t)gid * 8) = make_uint4(hv[0], hv[1], hv[2], hv[3]);
    *(uint4*)(bLo + (size_t)gid * 8) = make_uint4(lv[0], lv[1], lv[2], lv[3]);
}

// ---------------- K1: MFMA scan — 16 samples x all 10000 cols per block ----------------
__global__ __launch_bounds__(256) void vq_mfma(
    const ushort* __restrict__ aHi, const ushort* __restrict__ aLo,
    const ushort* __restrict__ bHi, const ushort* __restrict__ bLo,
    const float* __restrict__ c2f, const float* __restrict__ cm,
    const float* __restrict__ smp,
    float* __restrict__ out_q, float* __restrict__ out_idx, float* __restrict__ out_diff,
    int* __restrict__ flag)
{
    const int tid = threadIdx.x;
    const int lane = tid & 63, wav = tid >> 6;
    const int mt = blockIdx.x;
    const int s0 = mt * 16;

    // resident A fragments (4 k-steps, hi/lo)
    bf16x8 ah[4], al[4];
    {
        const uint4* aph = (const uint4*)(aHi + (size_t)mt * 4 * 64 * 8);
        const uint4* apl = (const uint4*)(aLo + (size_t)mt * 4 * 64 * 8);
#pragma unroll
        for (int ks = 0; ks < 4; ++ks) {
            ah[ks] = __builtin_bit_cast(bf16x8, aph[ks * 64 + lane]);
            al[ks] = __builtin_bit_cast(bf16x8, apl[ks * 64 + lane]);
        }
    }

    float v1[4], v2[4];
    int   i1[4];
#pragma unroll
    for (int j = 0; j < 4; ++j) { v1[j] = -3.0e38f; v2[j] = -3.0e38f; i1[j] = 0; }

#pragma unroll 1
    for (int et = wav; et < NTILE; et += 4) {
        const uint4* bph = (const uint4*)(bHi + (size_t)et * 4 * 64 * 8);
        const uint4* bpl = (const uint4*)(bLo + (size_t)et * 4 * 64 * 8);
        bf16x8 bh[4], bl[4];
#pragma unroll
        for (int ks = 0; ks < 4; ++ks) {
            bh[ks] = __builtin_bit_cast(bf16x8, bph[ks * 64 + lane]);
            bl[ks] = __builtin_bit_cast(bf16x8, bpl[ks * 64 + lane]);
        }
        f32x4 ahh = {0.f, 0.f, 0.f, 0.f}, ahl = ahh, alh = ahh;
#pragma unroll
        for (int ks = 0; ks < 4; ++ks) {
            ahh = __builtin_amdgcn_mfma_f32_16x16x32_bf16(ah[ks], bh[ks], ahh, 0, 0, 0);
            ahl = __builtin_amdgcn_mfma_f32_16x16x32_bf16(ah[ks], bl[ks], ahl, 0, 0, 0);
            alh = __builtin_amdgcn_mfma_f32_16x16x32_bf16(al[ks], bh[ks], alh, 0, 0, 0);
        }
        const int e = et * 16 + (lane & 15);
        const float c2e = c2f[e];
#pragma unroll
        for (int j = 0; j < 4; ++j) {
            float dot = ahh[j] + ahl[j] + alh[j];
            float sc = fmaf(-2.0f, dot, c2e);
            if (sc > v1[j]) { v2[j] = v1[j]; v1[j] = sc; i1[j] = e; }
            else if (sc > v2[j]) { v2[j] = sc; }
        }
    }

    // butterfly over the 16-lane col groups (rows are partitioned across groups)
#pragma unroll
    for (int j = 0; j < 4; ++j) {
#pragma unroll
        for (int m = 1; m < 16; m <<= 1) {
            float ov1 = __shfl_xor(v1[j], m, 64);
            int   oi1 = __shfl_xor(i1[j], m, 64);
            float ov2 = __shfl_xor(v2[j], m, 64);
            float nv2 = fmaxf(fminf(v1[j], ov1), fmaxf(v2[j], ov2));
            if (ov1 > v1[j] || (ov1 == v1[j] && oi1 < i1[j])) { v1[j] = ov1; i1[j] = oi1; }
            v2[j] = nv2;
        }
    }

    __shared__ float swv1[4][16], swv2[4][16];
    __shared__ int   swi[4][16];
    __shared__ int   fin[16];
    if ((lane & 15) == 0) {
        int g = lane >> 4;
#pragma unroll
        for (int j = 0; j < 4; ++j) {
            swv1[wav][g * 4 + j] = v1[j];
            swv2[wav][g * 4 + j] = v2[j];
            swi[wav][g * 4 + j]  = i1[j];
        }
    }
    __syncthreads();
    if (tid < 16) {
        float bv1 = swv1[0][tid]; int bi = swi[0][tid]; float bv2 = swv2[0][tid];
#pragma unroll
        for (int w = 1; w < 4; ++w) {
            float av1 = swv1[w][tid]; int ai = swi[w][tid]; float av2 = swv2[w][tid];
            float nv2 = fmaxf(fminf(bv1, av1), fmaxf(bv2, av2));
            if (av1 > bv1 || (av1 == bv1 && ai < bi)) { bv1 = av1; bi = ai; }
            bv2 = nv2;
        }
        fin[tid] = bi;
        out_idx[s0 + tid] = (float)bi;
        flag[s0 + tid] = (bv1 - bv2 < MARGIN) ? 1 : 0;
    }
    __syncthreads();

    // epilogue: gather + diff (16 threads/sample, 8 dims each)
    {
        const int s  = tid >> 4;
        const int d0 = (tid & 15) * 8;
        const int e  = fin[s];
        float a = 0.0f;
#pragma unroll
        for (int j = 0; j < 8; ++j) {
            int d = d0 + j;
            float q = cm[(size_t)d * NEMB + e];
            float x = smp[(size_t)(s0 + s) * DIM + d];
            out_q[(size_t)(s0 + s) * DIM + d] = q;
            float t = x - q;
            a = fmaf(t, t, a);
        }
#pragma unroll
        for (int m = 1; m < 16; m <<= 1) a += __shfl_xor(a, m, 64);
        if ((tid & 15) == 0) out_diff[s0 + s] = a * (1.0f / DIM);
    }
}

// ---------------- K3: exact f64 refine, one sample per block, early exit ----------------
__global__ __launch_bounds__(256) void vq_refine(
    const float* __restrict__ cm, const float* __restrict__ smp,
    const double* __restrict__ c2d, const int* __restrict__ flag,
    float* __restrict__ out_q, float* __restrict__ out_idx, float* __restrict__ out_diff)
{
    const int s = blockIdx.x;
    if (!flag[s]) return;
    const int tid = threadIdx.x;
    const int lane = tid & 63, wav = tid >> 6;

    __shared__ double svd[DIM];
    __shared__ double rwv[4];
    __shared__ int    rwe[4];
    __shared__ float  dsum[4];
    __shared__ int    fin;

    if (tid < DIM) svd[tid] = (double)smp[(size_t)s * DIM + tid];
    __syncthreads();

    double bv = -1.0e300; int be = 0;
#pragma unroll 1
    for (int e0 = tid * 4; e0 < NEMB; e0 += 256 * 4) {
        double dot[4] = {0.0, 0.0, 0.0, 0.0};
#pragma unroll 8
        for (int d = 0; d < DIM; ++d) {
            float4 cv = *(const float4*)(cm + (size_t)d * NEMB + e0);
            double sd = svd[d];
            dot[0] = fma((double)cv.x, sd, dot[0]);
            dot[1] = fma((double)cv.y, sd, dot[1]);
            dot[2] = fma((double)cv.z, sd, dot[2]);
            dot[3] = fma((double)cv.w, sd, dot[3]);
        }
#pragma unroll
        for (int k = 0; k < 4; ++k) {
            int e = e0 + k;
            double sc = fma(-2.0, dot[k], c2d[e]);
            if (sc > bv) { bv = sc; be = e; }
        }
    }
#pragma unroll
    for (int m = 1; m < 64; m <<= 1) {
        double ov = __shfl_xor(bv, m, 64);
        int    oe = __shfl_xor(be, m, 64);
        if (ov > bv || (ov == bv && oe < be)) { bv = ov; be = oe; }
    }
    if (lane == 0) { rwv[wav] = bv; rwe[wav] = be; }
    __syncthreads();
    if (tid == 0) {
        double v = rwv[0]; int e = rwe[0];
#pragma unroll
        for (int w = 1; w < 4; ++w)
            if (rwv[w] > v || (rwv[w] == v && rwe[w] < e)) { v = rwv[w]; e = rwe[w]; }
        fin = e;
        out_idx[s] = (float)e;
    }
    __syncthreads();
    const int e = fin;
    float t2 = 0.0f;
    if (tid < DIM) {
        float q = cm[(size_t)tid * NEMB + e];
        float x = smp[(size_t)s * DIM + tid];
        out_q[(size_t)s * DIM + tid] = q;
        float t = x - q;
        t2 = t * t;
    }
#pragma unroll
    for (int m = 1; m < 64; m <<= 1) t2 += __shfl_xor(t2, m, 64);
    if (lane == 0) dsum[wav] = t2;
    __syncthreads();
    if (tid == 0) out_diff[s] = (dsum[0] + dsum[1] + dsum[2] + dsum[3]) * (1.0f / DIM);
}

extern "C" void kernel_launch(void* const* d_in, const int* in_sizes, int n_in,
                              void* d_out, int out_size, void* d_ws, size_t ws_size,
                              hipStream_t stream) {
    const float* smp = (const float*)d_in[0];   // [8192,128]
    const float* cm  = (const float*)d_in[1];   // [128,10000]

    float* out      = (float*)d_out;
    float* out_q    = out;
    float* out_idx  = out + (size_t)NSAMP * DIM;
    float* out_diff = out_idx + NSAMP;

    char* ws = (char*)d_ws;
    double* c2d  = (double*)ws;                              // 80000 B
    float*  c2f  = (float*)(ws + 80000);                     // 40000 B
    ushort* aHi  = (ushort*)(ws + 120064);                   // 2 MB (16B aligned)
    ushort* aLo  = (ushort*)(ws + 120064 + 2097152);         // 2 MB
    ushort* bHi  = (ushort*)(ws + 120064 + 4194304);         // 2.56 MB
    ushort* bLo  = (ushort*)(ws + 120064 + 4194304 + 2560000);
    int*    flag = (int*)  (ws + 120064 + 4194304 + 5120000);// 32768 B

    prep_c2<<<(NEMB + 255) / 256, 256, 0, stream>>>(cm, c2d, c2f);
    prep_apk<<<512, 256, 0, stream>>>(smp, aHi, aLo);
    prep_bpk<<<NTILE, 256, 0, stream>>>(cm, bHi, bLo);
    vq_mfma<<<NSAMP / 16, 256, 0, stream>>>(aHi, aLo, bHi, bLo, c2f, cm, smp,
                                            out_q, out_idx, out_diff, flag);
    vq_refine<<<NSAMP, 256, 0, stream>>>(cm, smp, c2d, flag, out_q, out_idx, out_diff);
}